// Round 1
// baseline (1209.399 us; speedup 1.0000x reference)
//
#include <hip/hip_runtime.h>

// SE(3)-Transformer backbone, fp32, MI355X.
// Dims: B=16 N=64 FIN=16 C=32 D=4 (mg: l0=1, l1=3, l2=5, l3=7 -> 16) L=4 H=8 hd=4
// f layout: [b*64+n][c][mg] flat, 512 floats per node.
// nodefeats layout per node (1792 floats):
//   +0    sc_k[l*32+c]  (128)
//   +128  sc_v[l*32+c]  (128)
//   +256  id_k[c*16+mg] (512)
//   +768  id_v[c*16+mg] (512)
//   +1280 q   [c*16+mg] (512)

__device__ __forceinline__ int lof(int mg)   { return (mg==0)?0:((mg<4)?1:((mg<9)?2:3)); }
__device__ __forceinline__ int mgb_of(int l) { return (l==0)?0:((l==1)?1:((l==2)?4:9)); }

// ---------------- embed: f0 = h @ Wemb, higher degrees zero ----------------
__global__ __launch_bounds__(256) void embed_k(const float* __restrict__ h,
                                               const float* __restrict__ Wemb,
                                               float* __restrict__ f) {
  int idx = blockIdx.x * 256 + threadIdx.x;   // covers 16*64*512 = 524288
  int node = idx >> 9;
  int rem  = idx & 511;
  int c = rem >> 4, mg = rem & 15;
  float v = 0.f;
  if (mg == 0) {
    const float* hh = h + node * 16;
    #pragma unroll
    for (int i = 0; i < 16; i++) v += hh[i] * Wemb[i * 32 + c];
  }
  f[idx] = v;
}

// ---------------- per-node K/V/Q projections ----------------
__global__ __launch_bounds__(256) void nodefeats_k(const float* __restrict__ f,
    const float* __restrict__ Wk, const float* __restrict__ Wv,
    const float* __restrict__ Wq, float* __restrict__ nf, int li) {
  __shared__ __align__(16) float fl[512];
  const int node = blockIdx.x;
  const int tid = threadIdx.x;
  reinterpret_cast<float2*>(fl)[tid] =
      reinterpret_cast<const float2*>(f + (size_t)node * 512)[tid];
  __syncthreads();
  float* out = nf + (size_t)node * 1792;
  #pragma unroll
  for (int k = 0; k < 7; k++) {
    int o = tid + k * 256;
    float acc = 0.f;
    if (o < 128) {                       // sc_k
      int l = o >> 5, c = o & 31;
      const float* w = Wk + (size_t)(((li*4 + l)*2 + 0)*32 + c) * 32;
      #pragma unroll
      for (int i = 0; i < 32; i++) acc += w[i] * fl[i*16];
    } else if (o < 256) {                // sc_v
      int o2 = o - 128; int l = o2 >> 5, c = o2 & 31;
      const float* w = Wv + (size_t)(((li*4 + l)*2 + 0)*32 + c) * 32;
      #pragma unroll
      for (int i = 0; i < 32; i++) acc += w[i] * fl[i*16];
    } else if (o < 768) {                // id_k
      int o2 = o - 256; int c = o2 >> 4, mg = o2 & 15, l = lof(mg);
      const float* w = Wk + (size_t)(((li*4 + l)*2 + 1)*32 + c) * 32;
      #pragma unroll
      for (int i = 0; i < 32; i++) acc += w[i] * fl[i*16 + mg];
    } else if (o < 1280) {               // id_v
      int o2 = o - 768; int c = o2 >> 4, mg = o2 & 15, l = lof(mg);
      const float* w = Wv + (size_t)(((li*4 + l)*2 + 1)*32 + c) * 32;
      #pragma unroll
      for (int i = 0; i < 32; i++) acc += w[i] * fl[i*16 + mg];
    } else {                             // q
      int o2 = o - 1280; int c = o2 >> 4, mg = o2 & 15, l = lof(mg);
      const float* w = Wq + (size_t)((li*4 + l)*32 + c) * 32;
      #pragma unroll
      for (int i = 0; i < 32; i++) acc += w[i] * fl[i*16 + mg];
    }
    out[o] = acc;
  }
}

// ---------------- fused attention layer: one block per (b, dst) ----------------
__global__ __launch_bounds__(256) void attn_k(
    const float* __restrict__ f, const float* __restrict__ nf,
    float* __restrict__ fnext,
    const float* __restrict__ x, const int* __restrict__ bond,
    const float* __restrict__ rw1, const float* __restrict__ rb1,
    const float* __restrict__ rw2, const float* __restrict__ rb2,
    const float* __restrict__ Wself, const float* __restrict__ gnorm,
    const float* __restrict__ bnorm, int li) {
  __shared__ __align__(16) float Ysh[64][16];     // Y per source (mg layout); reused as o_lds in epilogue
  __shared__ float rinsh[64][8];                  // dist + 4 bond one-hots
  __shared__ float qsh[32 * 17];                  // q, padded stride 17 (bank spread)
  __shared__ __align__(16) float fdst[512];       // dst fiber (for Wself skip)
  __shared__ __align__(16) float hmid[4][32];     // radial hidden per edge-group; reused as fac in epilogue
  __shared__ float logitsg[4][9];                 // per-group logits [edge][head], padded
  __shared__ __align__(16) float r23g[4][256];    // per-group v-path r: [e][c*8 + l*2 + {0:r2*scv, 1:r3}]

  const int tid = threadIdx.x;
  const int bx  = blockIdx.x;
  const int b = bx >> 6, d = bx & 63;
  const int o0 = 2 * tid;
  const int lane = tid & 63;
  const int lw = tid >> 6;              // wave id == degree l of this thread's r-columns
  const int jj = (tid >> 4) & 3;        // radial path 0..3
  const int c0 = o0 & 31;               // even channel of the r-column pair
  const int hH = c0 >> 2;
  const int mgb = mgb_of(lw);
  const int Ml = 2 * lw + 1;

  // ---- block-start loads ----
  {
    const float2 qv = *reinterpret_cast<const float2*>(nf + (size_t)bx * 1792 + 1280 + o0);
    int qc = tid >> 3, qm = 2 * (tid & 7);
    qsh[qc * 17 + qm] = qv.x;
    qsh[qc * 17 + qm + 1] = qv.y;
    *reinterpret_cast<float2*>(fdst + o0) =
        *reinterpret_cast<const float2*>(f + (size_t)bx * 512 + o0);
  }
  if (tid < 64) {               // inline geometry for source s = tid
    const int s = tid;
    const float* xb = x + (size_t)b * 192;
    float xd = xb[d*3+0], yd = xb[d*3+1], zd = xb[d*3+2];
    float dx = xb[s*3+0] - xd, dy = xb[s*3+1] - yd, dz = xb[s*3+2] - zd;
    float dist = sqrtf(dx*dx + dy*dy + dz*dz + 1e-6f);
    float inv = 1.0f / dist;
    float xx = dx*inv, yy = dy*inv, zz = dz*inv;
    float* Y = Ysh[s];
    Y[0]  = 0.28209479177387814f;
    Y[1]  = 0.4886025119029199f * yy;
    Y[2]  = 0.4886025119029199f * zz;
    Y[3]  = 0.4886025119029199f * xx;
    Y[4]  = 1.0925484305920792f * xx * yy;
    Y[5]  = 1.0925484305920792f * yy * zz;
    Y[6]  = 0.31539156525252005f * (3.0f*zz*zz - 1.0f);
    Y[7]  = 1.0925484305920792f * xx * zz;
    Y[8]  = 0.5462742152960396f * (xx*xx - yy*yy);
    Y[9]  = 0.5900435899266435f * yy * (3.0f*xx*xx - yy*yy);
    Y[10] = 2.890611442640554f  * xx * yy * zz;
    Y[11] = 0.4570457994644658f * yy * (5.0f*zz*zz - 1.0f);
    Y[12] = 0.3731763325901154f * zz * (5.0f*zz*zz - 3.0f);
    Y[13] = 0.4570457994644658f * xx * (5.0f*zz*zz - 1.0f);
    Y[14] = 1.445305721320277f  * zz * (xx*xx - yy*yy);
    Y[15] = 0.5900435899266435f * xx * (xx*xx - yy*yy);
    rinsh[s][0] = dist;
    int bt = bond[(size_t)b * 4096 + d * 64 + s];
    bt = bt < 0 ? 0 : (bt > 4 ? 4 : bt);
    rinsh[s][1] = (bt == 1) ? 1.f : 0.f;
    rinsh[s][2] = (bt == 2) ? 1.f : 0.f;
    rinsh[s][3] = (bt == 3) ? 1.f : 0.f;
    rinsh[s][4] = (bt == 4) ? 1.f : 0.f;
  }

  // rw2 columns for this thread's 2 outputs, resident in registers
  float2 w2[32];
  #pragma unroll
  for (int i = 0; i < 32; i++)
    w2[i] = *reinterpret_cast<const float2*>(rw2 + ((size_t)li*32 + i) * 512 + o0);
  const float2 rbv = *reinterpret_cast<const float2*>(rb2 + li * 512 + o0);

  float w1r[5];
  #pragma unroll
  for (int i = 0; i < 5; i++) w1r[i] = rw1[(li*5 + i)*32 + (lane & 31)];
  const float b1r = rb1[li*32 + (lane & 31)];

  // o-accumulator slot decode (flat = c*16+mg, slots o0, o0+1)
  const int oc = tid >> 3;
  const int mg0 = 2 * (tid & 7), mg1 = mg0 + 1;
  const int l0 = lof(mg0), l1 = lof(mg1);
  const int ohh = oc >> 2;

  float m_run = -1e30f, l_run = 0.0f;
  float acc0 = 0.0f, acc1 = 0.0f;

  __syncthreads();

  for (int g = 0; g < 16; g++) {
    const int sb = g * 4;
    // Z: zero this group's logits
    if (tid < 36) (&logitsg[0][0])[tid] = 0.0f;
    // A: radial hidden (LN+relu) — wave lw handles edge lw
    {
      const int s = sb + lw;
      float pre = b1r;
      #pragma unroll
      for (int i = 0; i < 5; i++) pre += rinsh[s][i] * w1r[i];
      float mu = pre;
      #pragma unroll
      for (int k = 16; k >= 1; k >>= 1) mu += __shfl_xor(mu, k, 32);
      mu *= 0.03125f;
      float dv = pre - mu;
      float var = dv * dv;
      #pragma unroll
      for (int k = 16; k >= 1; k >>= 1) var += __shfl_xor(var, k, 32);
      var *= 0.03125f;
      float hm = fmaxf(dv * rsqrtf(var + 1e-6f), 0.0f);
      if (lane < 32) hmid[lw][lane] = hm;
    }
    __syncthreads();
    // B: r = hmid @ rw2 + rb2 for 4 edges, this thread's 2 columns
    float2 racc[4];
    #pragma unroll
    for (int e = 0; e < 4; e++) racc[e] = rbv;
    #pragma unroll
    for (int e = 0; e < 4; e++) {
      const float4* hp = reinterpret_cast<const float4*>(&hmid[e][0]);
      float rx = racc[e].x, ry = racc[e].y;
      #pragma unroll
      for (int i4 = 0; i4 < 8; i4++) {
        float4 h4 = hp[i4];
        float2 wa = w2[i4*4+0], wb = w2[i4*4+1], wc = w2[i4*4+2], wd = w2[i4*4+3];
        rx += h4.x*wa.x + h4.y*wb.x + h4.z*wc.x + h4.w*wd.x;
        ry += h4.x*wa.y + h4.y*wb.y + h4.z*wc.y + h4.w*wd.y;
      }
      racc[e].x = rx; racc[e].y = ry;
    }
    // C: logits partials (paths 0,1) / stage v-path r (paths 2,3)
    if (jj == 0) {
      #pragma unroll
      for (int e = 0; e < 4; e++) {
        const int s = sb + e;
        const float2 sck = *reinterpret_cast<const float2*>(
            nf + (size_t)(b*64 + s)*1792 + lw*32 + c0);
        float qy0 = 0.f, qy1 = 0.f;
        for (int m = 0; m < Ml; m++) {
          const float Yv = Ysh[s][mgb + m];
          qy0 += qsh[c0*17 + mgb + m] * Yv;
          qy1 += qsh[(c0+1)*17 + mgb + m] * Yv;
        }
        atomicAdd(&logitsg[e][hH], racc[e].x*sck.x*qy0 + racc[e].y*sck.y*qy1);
      }
    } else if (jj == 1) {
      #pragma unroll
      for (int e = 0; e < 4; e++) {
        const int s = sb + e;
        const float* idk = nf + (size_t)(b*64 + s)*1792 + 256;
        float a0 = 0.f, a1 = 0.f;
        for (int m = 0; m < Ml; m++) {
          a0 += idk[c0*16 + mgb + m]     * qsh[c0*17 + mgb + m];
          a1 += idk[(c0+1)*16 + mgb + m] * qsh[(c0+1)*17 + mgb + m];
        }
        atomicAdd(&logitsg[e][hH], racc[e].x*a0 + racc[e].y*a1);
      }
    } else if (jj == 2) {
      #pragma unroll
      for (int e = 0; e < 4; e++) {
        const int s = sb + e;
        const float2 scv = *reinterpret_cast<const float2*>(
            nf + (size_t)(b*64 + s)*1792 + 128 + lw*32 + c0);
        r23g[e][c0*8 + lw*2]     = racc[e].x * scv.x;
        r23g[e][(c0+1)*8 + lw*2] = racc[e].y * scv.y;
      }
    } else {
      #pragma unroll
      for (int e = 0; e < 4; e++) {
        r23g[e][c0*8 + lw*2 + 1]     = racc[e].x;
        r23g[e][(c0+1)*8 + lw*2 + 1] = racc[e].y;
      }
    }
    __syncthreads();
    // D: online-softmax update of this thread's 2 o-slots
    {
      float lg[4];
      #pragma unroll
      for (int e = 0; e < 4; e++) {
        const int s = sb + e;
        float raw = logitsg[e][ohh];
        lg[e] = (s == d) ? -1e9f : raw * 0.125f;   // scale = 1/sqrt(hd*16)
      }
      float m4 = fmaxf(fmaxf(lg[0], lg[1]), fmaxf(lg[2], lg[3]));
      float m_new = fmaxf(m_run, m4);
      float resc = __expf(m_run - m_new);
      acc0 *= resc; acc1 *= resc; l_run *= resc;
      #pragma unroll
      for (int e = 0; e < 4; e++) {
        const int s = sb + e;
        float w = __expf(lg[e] - m_new);
        l_run += w;
        const float2 iv = *reinterpret_cast<const float2*>(
            nf + (size_t)(b*64 + s)*1792 + 768 + o0);
        const float2 ra = *reinterpret_cast<const float2*>(&r23g[e][oc*8 + l0*2]);
        const float2 rb = *reinterpret_cast<const float2*>(&r23g[e][oc*8 + l1*2]);
        float v0 = ra.x * Ysh[s][mg0] + ra.y * iv.x;
        float v1 = rb.x * Ysh[s][mg1] + rb.y * iv.y;
        acc0 += w * v0;
        acc1 += w * v1;
      }
      m_run = m_new;
    }
    __syncthreads();
  }

  // ---- epilogue: normalize, Wself skip, NormSE3 gate, write ----
  const float invl = 1.0f / l_run;
  acc0 *= invl; acc1 *= invl;
  {
    const float* w0 = Wself + (size_t)((li*4 + l0)*32 + oc) * 32;
    const float* w1 = Wself + (size_t)((li*4 + l1)*32 + oc) * 32;
    #pragma unroll
    for (int i = 0; i < 32; i++) {
      acc0 += w0[i] * fdst[i*16 + mg0];
      acc1 += w1[i] * fdst[i*16 + mg1];
    }
  }
  float* osh = &Ysh[0][0];    // reuse (Ysh no longer needed)
  osh[o0] = acc0; osh[o0 + 1] = acc1;
  __syncthreads();
  if (tid < 128) {
    const int c2 = tid >> 2, l2 = tid & 3;
    const int mb = mgb_of(l2), M2 = 2*l2 + 1;
    float ss = 0.f;
    for (int m = 0; m < M2; m++) { float v = osh[c2*16 + mb + m]; ss += v*v; }
    const float nrm = sqrtf(ss + 1e-6f);
    const float gg = gnorm[(li*4 + l2)*32 + c2];
    const float bb = bnorm[(li*4 + l2)*32 + c2];
    const float sg = fmaxf(gg*nrm + bb, 0.f);
    (&hmid[0][0])[c2*4 + l2] = sg / nrm;
  }
  __syncthreads();
  const float fac0 = (&hmid[0][0])[oc*4 + l0];
  const float fac1 = (&hmid[0][0])[oc*4 + l1];
  *reinterpret_cast<float2*>(fnext + (size_t)bx * 512 + o0) =
      make_float2(acc0 * fac0, acc1 * fac1);
}

// ---------------- readout: invariant norms -> mean over nodes -> Wfinal ----------------
__global__ __launch_bounds__(256) void readout_k(const float* __restrict__ f,
    const float* __restrict__ Wfinal, const float* __restrict__ bfinal,
    float* __restrict__ out) {
  __shared__ float invs[2][128];
  __shared__ float inv1[128];
  const int b = blockIdx.x;
  const int tid = threadIdx.x;
  const int j = tid & 127, half = tid >> 7;
  float p = 0.f;
  for (int n = half*32; n < half*32 + 32; n++) {
    const float* fn = f + (size_t)(b*64 + n) * 512;
    float v;
    if (j < 32) {
      v = fn[j*16];
    } else {
      int l = j >> 5, c = j & 31;
      int mb = mgb_of(l), M = 2*l + 1;
      float ss = 0.f;
      for (int m = 0; m < M; m++) { float t = fn[c*16 + mb + m]; ss += t*t; }
      v = sqrtf(ss + 1e-6f);
    }
    p += v;
  }
  invs[half][j] = p;
  __syncthreads();
  if (tid < 128) inv1[tid] = (invs[0][tid] + invs[1][tid]) * (1.0f / 64.0f);
  __syncthreads();
  if (tid < 128) {
    float acc = bfinal[tid];
    for (int k = 0; k < 128; k++) acc += inv1[k] * Wfinal[k*128 + tid];
    out[b*128 + tid] = acc;
  }
}

extern "C" void kernel_launch(void* const* d_in, const int* in_sizes, int n_in,
                              void* d_out, int out_size, void* d_ws, size_t ws_size,
                              hipStream_t stream) {
  (void)in_sizes; (void)n_in; (void)out_size; (void)ws_size;
  const float* h      = (const float*)d_in[0];
  const float* x      = (const float*)d_in[1];
  const int*   bond   = (const int*)d_in[2];
  const float* Wemb   = (const float*)d_in[3];
  const float* rw1    = (const float*)d_in[4];
  const float* rb1    = (const float*)d_in[5];
  const float* rw2    = (const float*)d_in[6];
  const float* rb2    = (const float*)d_in[7];
  const float* Wk     = (const float*)d_in[8];
  const float* Wv     = (const float*)d_in[9];
  const float* Wq     = (const float*)d_in[10];
  const float* Wself  = (const float*)d_in[11];
  const float* gnorm  = (const float*)d_in[12];
  const float* bnorm  = (const float*)d_in[13];
  const float* Wfinal = (const float*)d_in[14];
  const float* bfinal = (const float*)d_in[15];
  float* out = (float*)d_out;

  float* ws = (float*)d_ws;
  float* fA = ws;                       // 524288 floats
  float* fB = ws + 524288;              // 524288 floats
  float* nf = ws + 2 * 524288;          // 1024*1792 floats

  embed_k<<<2048, 256, 0, stream>>>(h, Wemb, fA);

  float* fc = fA; float* fn2 = fB;
  for (int li = 0; li < 4; li++) {
    nodefeats_k<<<1024, 256, 0, stream>>>(fc, Wk, Wv, Wq, nf, li);
    attn_k<<<1024, 256, 0, stream>>>(fc, nf, fn2, x, bond,
                                     rw1, rb1, rw2, rb2, Wself, gnorm, bnorm, li);
    float* t = fc; fc = fn2; fn2 = t;
  }

  readout_k<<<16, 256, 0, stream>>>(fc, Wfinal, bfinal, out);
}